// Round 5
// baseline (268.232 us; speedup 1.0000x reference)
//
#include <hip/hip_runtime.h>

#define BB 16
#define SS 2048
#define DD 128
#define INVSCALE 0.08838834764831845f  // 1/sqrt(128)

typedef __attribute__((ext_vector_type(4))) float f32x4;
typedef __attribute__((ext_vector_type(8))) short short8;
typedef __attribute__((ext_vector_type(4))) unsigned short us4;
typedef __attribute__((ext_vector_type(8))) unsigned short us8;

__device__ inline unsigned short f2bf(float f) {
    unsigned u = __float_as_uint(f);
    u += 0x7fffu + ((u >> 16) & 1u);   // round-to-nearest-even
    return (unsigned short)(u >> 16);
}

// XOR swizzles (swzA: 256B rows; swzB: 128B rows)
__device__ inline int swzA(int row, int col) {
    int byteoff = (row << 8) + ((col >> 3) << 4);
    byteoff ^= (row & 7) << 4;
    return (byteoff >> 1) + (col & 7);
}
__device__ inline int swzB(int row, int col) {
    int byteoff = (row << 7) + ((col >> 3) << 4);
    byteoff ^= (row & 7) << 4;
    return (byteoff >> 1) + (col & 7);
}

// ---------------------------------------------------------------------------
// conv: Q,K fp32 -> bf16; mask int -> bf16 (1.0/0.0)
// ---------------------------------------------------------------------------
__global__ __launch_bounds__(256) void conv_bf16_kernel(
    const float* __restrict__ Q, const float* __restrict__ K,
    const int* __restrict__ mask,
    unsigned short* __restrict__ Qb, unsigned short* __restrict__ Kb,
    unsigned short* __restrict__ maskbf)
{
    int idx = blockIdx.x * blockDim.x + threadIdx.x;
    const int total = BB * SS * DD / 4;
    for (int i = idx; i < total; i += gridDim.x * blockDim.x) {
        f32x4 q = reinterpret_cast<const f32x4*>(Q)[i];
        f32x4 k = reinterpret_cast<const f32x4*>(K)[i];
        us4 qh, kh;
        for (int j = 0; j < 4; ++j) { qh[j] = f2bf(q[j]); kh[j] = f2bf(k[j]); }
        reinterpret_cast<us4*>(Qb)[i] = qh;
        reinterpret_cast<us4*>(Kb)[i] = kh;
    }
    if (idx < BB * SS)
        maskbf[idx] = mask[idx] ? (unsigned short)0x3F80 : (unsigned short)0;
}

// ---------------------------------------------------------------------------
// vt: V (b,k,d) fp32 -> VT (b,d,k) bf16
// ---------------------------------------------------------------------------
__global__ __launch_bounds__(256) void vt_kernel(
    const float* __restrict__ V, unsigned short* __restrict__ VT)
{
    __shared__ unsigned short tile[64 * 136];
    int b = blockIdx.y, k0 = blockIdx.x << 6;
    int t = threadIdx.x;
    const float* Vg = V + ((size_t)b * SS + k0) * DD;
    for (int i = 0; i < 8; ++i) {
        int f4 = (i << 8) + t;
        int k  = f4 >> 5;
        int n  = (f4 & 31) << 2;
        f32x4 v = reinterpret_cast<const f32x4*>(Vg)[f4];
        us4 h;
        for (int j = 0; j < 4; ++j) h[j] = f2bf(v[j]);
        *reinterpret_cast<us4*>(&tile[k * 136 + n]) = h;
    }
    __syncthreads();
    unsigned short* outp = VT + (size_t)b * DD * SS;
    for (int i = 0; i < 4; ++i) {
        int id = (i << 8) + t;
        int n  = id >> 3;
        int c8 = id & 7;
        us8 o;
        for (int j = 0; j < 8; ++j) o[j] = tile[((c8 << 3) + j) * 136 + n];
        *reinterpret_cast<us8*>(&outp[(size_t)n * SS + k0 + (c8 << 3)]) = o;
    }
}

// ---------------------------------------------------------------------------
// flashA: barrier-free. grid 512 (B x qblk16 x kvhalf2, XCD-grouped), 256 thr,
// 4 waves x 32 q-rows. Fragments gathered direct from L2. Writes partial
// unnormalized O and partial L. Only LDS: per-wave 4KB P roundtrip.
// ---------------------------------------------------------------------------
__global__ __launch_bounds__(256, 2) void flashA_kernel(
    const unsigned short* __restrict__ Qb, const unsigned short* __restrict__ Kb,
    const unsigned short* __restrict__ VT, const unsigned short* __restrict__ maskbf,
    float* __restrict__ Op0, float* __restrict__ Op1, float* __restrict__ Lp)
{
    __shared__ unsigned short Ps[4 * 2048];   // 4 waves x 32q x 64k bf16

    const int id = blockIdx.x;
    const int xcd = id & 7, j = id >> 3;
    const int b   = (xcd << 1) | (j >> 5);
    const int rem = j & 31;
    const int half = rem >> 4, qb = rem & 15;
    const int q0 = qb << 7;
    const int kvbase = half << 10;

    const int t = threadIdx.x, lane = t & 63, w = t >> 6;
    const int lr = lane & 15, lg = lane >> 4;

    const unsigned short* Kbb = Kb + (size_t)b * SS * DD;
    const unsigned short* Vbb = VT + (size_t)b * DD * SS;
    const unsigned short* Mbb = maskbf + (size_t)b * SS;

    // Q fragments (B-operand): q = q0 + w*32 + m*16 + lr
    const unsigned short* Qp = Qb + ((size_t)b * SS + q0 + w * 32) * DD;
    short8 qf[2][4];
    for (int m = 0; m < 2; ++m)
        for (int kb = 0; kb < 4; ++kb)
            qf[m][kb] = *reinterpret_cast<const short8*>(
                Qp + (size_t)(m * 16 + lr) * DD + kb * 32 + lg * 8);

    f32x4 oacc[2][8] = {};
    float rsum[2] = {0.f, 0.f};
    unsigned short* Pw = &Ps[w * 2048];

    for (int kt = 0; kt < 16; ++kt) {
        const int kv0 = kvbase + (kt << 6);

        // S^T = K.Q^T : A-frag gather of K rows from L2
        f32x4 sacc[2][4] = {};
        for (int kb = 0; kb < 4; ++kb) {
            short8 kf[4];
            for (int n = 0; n < 4; ++n)
                kf[n] = *reinterpret_cast<const short8*>(
                    Kbb + (size_t)(kv0 + n * 16 + lr) * DD + kb * 32 + lg * 8);
            for (int n = 0; n < 4; ++n)
                for (int m = 0; m < 2; ++m)
                    sacc[m][n] = __builtin_amdgcn_mfma_f32_16x16x32_bf16(
                        kf[n], qf[m][kb], sacc[m][n], 0, 0, 0);
        }

        // p = exp(s)*mask; rowsum; stash bf16 P in wave-local LDS
        for (int n = 0; n < 4; ++n) {
            us4 mb = *reinterpret_cast<const us4*>(Mbb + kv0 + n * 16 + lg * 4);
            for (int m = 0; m < 2; ++m) {
                us4 h;
                for (int r = 0; r < 4; ++r) {
                    float mf = __uint_as_float((unsigned)mb[r] << 16);
                    float p  = __expf(sacc[m][n][r] * INVSCALE) * mf;
                    rsum[m] += p;
                    h[r] = f2bf(p);
                }
                *reinterpret_cast<us4*>(&Pw[swzB(m * 16 + lr, n * 16 + lg * 4)]) = h;
            }
        }
        asm volatile("s_waitcnt lgkmcnt(0)" ::: "memory");
        __builtin_amdgcn_sched_barrier(0);

        // O += P*V : B-frag gather of VT rows from L2
        for (int kb2 = 0; kb2 < 2; ++kb2) {
            short8 pf[2];
            for (int m = 0; m < 2; ++m)
                pf[m] = *reinterpret_cast<const short8*>(
                    &Pw[swzB(m * 16 + lr, kb2 * 32 + lg * 8)]);
            for (int nd = 0; nd < 8; ++nd) {
                short8 vf = *reinterpret_cast<const short8*>(
                    Vbb + (size_t)(nd * 16 + lr) * SS + kv0 + kb2 * 32 + lg * 8);
                for (int m = 0; m < 2; ++m)
                    oacc[m][nd] = __builtin_amdgcn_mfma_f32_16x16x32_bf16(
                        pf[m], vf, oacc[m][nd], 0, 0, 0);
            }
        }
    }

    // reduce L across lg groups; write partial L and unnormalized partial O
    for (int m = 0; m < 2; ++m) {
        rsum[m] += __shfl_xor(rsum[m], 16, 64);
        rsum[m] += __shfl_xor(rsum[m], 32, 64);
    }
    if (lane < 16)
        for (int m = 0; m < 2; ++m)
            Lp[(size_t)half * BB * SS + (size_t)b * SS + q0 + w * 32 + m * 16 + lane] = rsum[m];

    float* Op = half ? Op1 : Op0;
    float* Og = Op + ((size_t)b * SS + q0 + w * 32) * DD;
    for (int m = 0; m < 2; ++m)
        for (int nd = 0; nd < 8; ++nd)
            for (int r = 0; r < 4; ++r)
                Og[(size_t)(m * 16 + lg * 4 + r) * DD + nd * 16 + lr] = oacc[m][nd][r];
}

// ---------------------------------------------------------------------------
// combine: O = (O0+O1) * inv(L0+L1); write invLg for pstore. grid 4096 x 256.
// ---------------------------------------------------------------------------
__global__ __launch_bounds__(256) void combine_kernel(
    const float* __restrict__ Op0, const float* __restrict__ Op1,
    const float* __restrict__ Lp, float* __restrict__ O, float* __restrict__ invLg)
{
    int i = blockIdx.x * 256 + threadIdx.x;   // f32x4 index, total 1048576
    int row = i >> 5;                         // 32 f32x4 per row of 128
    float L = Lp[row] + Lp[BB * SS + row];
    float il = L > 0.f ? 1.f / L : 0.f;
    f32x4 a = reinterpret_cast<const f32x4*>(Op0)[i];
    f32x4 c = reinterpret_cast<const f32x4*>(Op1)[i];
    f32x4 o;
    for (int r = 0; r < 4; ++r) o[r] = (a[r] + c[r]) * il;
    reinterpret_cast<f32x4*>(O)[i] = o;
    if ((i & 31) == 0) invLg[row] = il;
}

// ---------------------------------------------------------------------------
// pstore: barrier-free, LDS-free. grid 1024 (B x qblk16 x kvquarter4), 256
// thr, 4 waves x 32 q. Recomputes S^T with identical op order, writes
// P = exp*mask*invL as coalesced f32x4.
// ---------------------------------------------------------------------------
__global__ __launch_bounds__(256, 4) void pstore_kernel(
    const unsigned short* __restrict__ Qb, const unsigned short* __restrict__ Kb,
    const unsigned short* __restrict__ maskbf, const float* __restrict__ invLg,
    float* __restrict__ P)
{
    const int id = blockIdx.x;
    const int xcd = id & 7, j = id >> 3;
    const int b   = (xcd << 1) | (j >> 6);
    const int rem = j & 63;
    const int kvq = rem >> 4, qb = rem & 15;
    const int q0 = qb << 7, kvbase = kvq << 9;

    const int t = threadIdx.x, lane = t & 63, w = t >> 6;
    const int lr = lane & 15, lg = lane >> 4;

    const unsigned short* Kbb = Kb + (size_t)b * SS * DD;
    const unsigned short* Mbb = maskbf + (size_t)b * SS;

    const unsigned short* Qp = Qb + ((size_t)b * SS + q0 + w * 32) * DD;
    short8 qf[2][4];
    for (int m = 0; m < 2; ++m)
        for (int kb = 0; kb < 4; ++kb)
            qf[m][kb] = *reinterpret_cast<const short8*>(
                Qp + (size_t)(m * 16 + lr) * DD + kb * 32 + lg * 8);

    float il[2];
    for (int m = 0; m < 2; ++m)
        il[m] = invLg[(size_t)b * SS + q0 + w * 32 + m * 16 + lr];

    for (int kt = 0; kt < 8; ++kt) {
        const int kv0 = kvbase + (kt << 6);
        f32x4 sacc[2][4] = {};
        for (int kb = 0; kb < 4; ++kb) {
            short8 kf[4];
            for (int n = 0; n < 4; ++n)
                kf[n] = *reinterpret_cast<const short8*>(
                    Kbb + (size_t)(kv0 + n * 16 + lr) * DD + kb * 32 + lg * 8);
            for (int n = 0; n < 4; ++n)
                for (int m = 0; m < 2; ++m)
                    sacc[m][n] = __builtin_amdgcn_mfma_f32_16x16x32_bf16(
                        kf[n], qf[m][kb], sacc[m][n], 0, 0, 0);
        }
        for (int m = 0; m < 2; ++m) {
            float* Pp = P + ((size_t)b * SS + q0 + w * 32 + m * 16 + lr) * SS + kv0;
            for (int n = 0; n < 4; ++n) {
                us4 mb = *reinterpret_cast<const us4*>(Mbb + kv0 + n * 16 + lg * 4);
                f32x4 out;
                for (int r = 0; r < 4; ++r) {
                    float mf = __uint_as_float((unsigned)mb[r] << 16);
                    out[r] = __expf(sacc[m][n][r] * INVSCALE) * mf * il[m];
                }
                *reinterpret_cast<f32x4*>(Pp + n * 16 + lg * 4) = out;
            }
        }
    }
}

// ---------------------------------------------------------------------------
// Fallback pipeline (no workspace requirements): round-1 kernels
// ---------------------------------------------------------------------------
__global__ __launch_bounds__(256) void qk_exp_kernel(
    const float* __restrict__ Q, const float* __restrict__ Kin,
    const int* __restrict__ mask, float* __restrict__ P)
{
    __shared__ unsigned short Qs[128 * 128];
    __shared__ unsigned short Ks[128 * 128];
    const int b  = blockIdx.z;
    const int m0 = blockIdx.y << 7;
    const int n0 = blockIdx.x << 7;
    const int t  = threadIdx.x;
    const float* Qp = Q   + ((size_t)b * SS + m0) * DD;
    const float* Kp = Kin + ((size_t)b * SS + n0) * DD;
    for (int i = 0; i < 16; ++i) {
        int f4  = (i << 8) + t;
        int row = f4 >> 5;
        int col = (f4 & 31) << 2;
        f32x4 q = reinterpret_cast<const f32x4*>(Qp)[f4];
        f32x4 k = reinterpret_cast<const f32x4*>(Kp)[f4];
        us4 qh, kh;
        for (int jj = 0; jj < 4; ++jj) { qh[jj] = f2bf(q[jj]); kh[jj] = f2bf(k[jj]); }
        *reinterpret_cast<us4*>(&Qs[swzA(row, col)]) = qh;
        *reinterpret_cast<us4*>(&Ks[swzA(row, col)]) = kh;
    }
    __syncthreads();
    const int lane = t & 63, wid = t >> 6;
    const int wr = wid >> 1, wc = wid & 1;
    const int lr = lane & 15, lg = lane >> 4;
    f32x4 acc[4][4] = {};
    for (int kb = 0; kb < 4; ++kb) {
        short8 a[4], bq[4];
        int kcol = (kb << 5) + (lg << 3);
        for (int m = 0; m < 4; ++m)
            a[m] = *reinterpret_cast<const short8*>(&Qs[swzA((wr << 6) + (m << 4) + lr, kcol)]);
        for (int n = 0; n < 4; ++n)
            bq[n] = *reinterpret_cast<const short8*>(&Ks[swzA((wc << 6) + (n << 4) + lr, kcol)]);
        for (int m = 0; m < 4; ++m)
            for (int n = 0; n < 4; ++n)
                acc[m][n] = __builtin_amdgcn_mfma_f32_16x16x32_bf16(a[m], bq[n], acc[m][n], 0, 0, 0);
    }
    const int* am = mask + (size_t)b * SS;
    for (int n = 0; n < 4; ++n) {
        int col = n0 + (wc << 6) + (n << 4) + lr;
        bool allow = am[col] != 0;
        for (int m = 0; m < 4; ++m) {
            int rowb = m0 + (wr << 6) + (m << 4) + (lg << 2);
            float* Pp = P + ((size_t)b * SS + rowb) * SS + col;
            for (int r = 0; r < 4; ++r) {
                float p = allow ? __expf(acc[m][n][r] * INVSCALE) : 0.0f;
                Pp[(size_t)r * SS] = p;
            }
        }
    }
}

__global__ __launch_bounds__(256) void norm_kernel(float* __restrict__ P)
{
    int row  = (blockIdx.x << 2) + (threadIdx.x >> 6);
    int lane = threadIdx.x & 63;
    float* Pr = P + (size_t)row * SS;
    f32x4 v[8];
    float sum = 0.f;
    for (int i = 0; i < 8; ++i) {
        v[i] = reinterpret_cast<f32x4*>(Pr)[(i << 6) + lane];
        sum += v[i][0] + v[i][1] + v[i][2] + v[i][3];
    }
    for (int off = 1; off < 64; off <<= 1) sum += __shfl_xor(sum, off, 64);
    float inv = sum > 0.f ? 1.f / sum : 0.f;
    for (int i = 0; i < 8; ++i) {
        f32x4 wv = v[i];
        for (int jj = 0; jj < 4; ++jj) wv[jj] *= inv;
        reinterpret_cast<f32x4*>(Pr)[(i << 6) + lane] = wv;
    }
}

__global__ __launch_bounds__(256) void pv_fallback_kernel(
    const float* __restrict__ P, const float* __restrict__ V, float* __restrict__ O)
{
    __shared__ unsigned short Ws[64 * 64];
    const int b  = blockIdx.y;
    const int m0 = blockIdx.x << 6;
    const int t  = threadIdx.x, lane = t & 63, wid = t >> 6;
    const int wr = wid >> 1, wc = wid & 1;
    const int lr = lane & 15, lg = lane >> 4;
    const float* Pg = P + ((size_t)b * SS + m0) * SS;
    f32x4 acc[2][4] = {};
    for (int k0 = 0; k0 < SS; k0 += 64) {
        __syncthreads();
        for (int i = 0; i < 4; ++i) {
            int f4  = (i << 8) + t;
            int row = f4 >> 4;
            int col = (f4 & 15) << 2;
            f32x4 wv = *reinterpret_cast<const f32x4*>(Pg + (size_t)row * SS + k0 + col);
            us4 h;
            for (int jj = 0; jj < 4; ++jj) h[jj] = f2bf(wv[jj]);
            *reinterpret_cast<us4*>(&Ws[swzB(row, col)]) = h;
        }
        __syncthreads();
        for (int kk = 0; kk < 64; kk += 32) {
            short8 a[2], bv[4];
            int kcol = kk + (lg << 3);
            for (int m = 0; m < 2; ++m)
                a[m] = *reinterpret_cast<const short8*>(&Ws[swzB((wr << 5) + (m << 4) + lr, kcol)]);
            for (int n = 0; n < 4; ++n) {
                int col = (wc << 6) + (n << 4) + lr;
                const float* vp = V + ((size_t)b * SS + k0 + kcol) * DD + col;
                short8 x;
                for (int jj = 0; jj < 8; ++jj) x[jj] = (short)f2bf(vp[(size_t)jj * DD]);
                bv[n] = x;
            }
            for (int m = 0; m < 2; ++m)
                for (int n = 0; n < 4; ++n)
                    acc[m][n] = __builtin_amdgcn_mfma_f32_16x16x32_bf16(a[m], bv[n], acc[m][n], 0, 0, 0);
        }
    }
    float* Og = O + ((size_t)b * SS + m0) * DD;
    for (int m = 0; m < 2; ++m)
        for (int n = 0; n < 4; ++n)
            for (int r = 0; r < 4; ++r)
                Og[(size_t)((wr << 5) + (m << 4) + (lg << 2) + r) * DD
                   + (wc << 6) + (n << 4) + lr] = acc[m][n][r];
}

// ---------------------------------------------------------------------------
extern "C" void kernel_launch(void* const* d_in, const int* in_sizes, int n_in,
                              void* d_out, int out_size, void* d_ws, size_t ws_size,
                              hipStream_t stream)
{
    const float* Q  = (const float*)d_in[0];
    const float* K  = (const float*)d_in[1];
    const float* V  = (const float*)d_in[2];
    const int* mask = (const int*)d_in[3];
    float* O = (float*)d_out;
    float* P = O + (size_t)BB * SS * DD;

    const size_t nE = (size_t)BB * SS * DD;   // 4194304 elements per tensor
    const size_t need = 3 * nE * sizeof(unsigned short)
                      + (size_t)BB * SS * sizeof(unsigned short)
                      + 3 * (size_t)BB * SS * sizeof(float) + 256;

    if (ws_size >= need) {
        unsigned short* Qb     = (unsigned short*)d_ws;
        unsigned short* Kb     = Qb + nE;
        unsigned short* VT     = Kb + nE;
        unsigned short* maskbf = VT + nE;
        float* Lp    = (float*)(maskbf + (size_t)BB * SS);   // 2 * BB*SS
        float* invLg = Lp + 2 * (size_t)BB * SS;
        // partial O buffers live in the P region (overwritten by pstore later)
        float* Op0 = P;
        float* Op1 = P + nE;

        conv_bf16_kernel<<<1024, 256, 0, stream>>>(Q, K, mask, Qb, Kb, maskbf);
        vt_kernel<<<dim3(SS / 64, BB), 256, 0, stream>>>(V, VT);
        flashA_kernel<<<512, 256, 0, stream>>>(Qb, Kb, VT, maskbf, Op0, Op1, Lp);
        combine_kernel<<<4096, 256, 0, stream>>>(Op0, Op1, Lp, O, invLg);
        pstore_kernel<<<1024, 256, 0, stream>>>(Qb, Kb, maskbf, invLg, P);
    } else {
        qk_exp_kernel<<<dim3(SS / 128, SS / 128, BB), 256, 0, stream>>>(Q, K, mask, P);
        norm_kernel<<<(BB * SS) / 4, 256, 0, stream>>>(P);
        pv_fallback_kernel<<<dim3(SS / 64, BB), 256, 0, stream>>>(P, V, O);
    }
}

// Round 6
// 143.901 us; speedup vs baseline: 1.8640x; 1.8640x over previous
//
#include <hip/hip_runtime.h>

#define BB 16
#define SS 2048
#define DD 128
// exp(s/sqrt(128)) = 2^(s * CE),  CE = log2(e)/sqrt(128)
#define CE (0.08838834764831845f * 1.4426950408889634f)

typedef __attribute__((ext_vector_type(4))) float f32x4;
typedef __attribute__((ext_vector_type(8))) short short8;
typedef __attribute__((ext_vector_type(4))) unsigned short us4;
typedef __attribute__((ext_vector_type(8))) unsigned short us8;

__device__ inline unsigned short f2bf(float f) {
    unsigned u = __float_as_uint(f);
    u += 0x7fffu + ((u >> 16) & 1u);   // round-to-nearest-even
    return (unsigned short)(u >> 16);
}

// XOR swizzles (swzA: 256B rows; swzB: 128B rows)
__device__ inline int swzA(int row, int col) {
    int byteoff = (row << 8) + ((col >> 3) << 4);
    byteoff ^= (row & 7) << 4;
    return (byteoff >> 1) + (col & 7);
}
__device__ inline int swzB(int row, int col) {
    int byteoff = (row << 7) + ((col >> 3) << 4);
    byteoff ^= (row & 7) << 4;
    return (byteoff >> 1) + (col & 7);
}

// ---------------------------------------------------------------------------
// conv: Q,K fp32 -> bf16; mask int -> fp32 additive (0 / -inf)
// ---------------------------------------------------------------------------
__global__ __launch_bounds__(256) void conv_bf16_kernel(
    const float* __restrict__ Q, const float* __restrict__ K,
    const int* __restrict__ mask,
    unsigned short* __restrict__ Qb, unsigned short* __restrict__ Kb,
    float* __restrict__ maskAdd)
{
    int idx = blockIdx.x * blockDim.x + threadIdx.x;
    const int total = BB * SS * DD / 4;
    for (int i = idx; i < total; i += gridDim.x * blockDim.x) {
        f32x4 q = reinterpret_cast<const f32x4*>(Q)[i];
        f32x4 k = reinterpret_cast<const f32x4*>(K)[i];
        us4 qh, kh;
        for (int j = 0; j < 4; ++j) { qh[j] = f2bf(q[j]); kh[j] = f2bf(k[j]); }
        reinterpret_cast<us4*>(Qb)[i] = qh;
        reinterpret_cast<us4*>(Kb)[i] = kh;
    }
    if (idx < BB * SS)
        maskAdd[idx] = mask[idx] ? 0.0f : __int_as_float(0xff800000); // -inf
}

// ---------------------------------------------------------------------------
// vt: V (b,k,d) fp32 -> VT (b,d,k) bf16
// ---------------------------------------------------------------------------
__global__ __launch_bounds__(256) void vt_kernel(
    const float* __restrict__ V, unsigned short* __restrict__ VT)
{
    __shared__ unsigned short tile[64 * 136];
    int b = blockIdx.y, k0 = blockIdx.x << 6;
    int t = threadIdx.x;
    const float* Vg = V + ((size_t)b * SS + k0) * DD;
    for (int i = 0; i < 8; ++i) {
        int f4 = (i << 8) + t;
        int k  = f4 >> 5;
        int n  = (f4 & 31) << 2;
        f32x4 v = reinterpret_cast<const f32x4*>(Vg)[f4];
        us4 h;
        for (int j = 0; j < 4; ++j) h[j] = f2bf(v[j]);
        *reinterpret_cast<us4*>(&tile[k * 136 + n]) = h;
    }
    __syncthreads();
    unsigned short* outp = VT + (size_t)b * DD * SS;
    for (int i = 0; i < 4; ++i) {
        int id = (i << 8) + t;
        int n  = id >> 3;
        int c8 = id & 7;
        us8 o;
        for (int j = 0; j < 8; ++j) o[j] = tile[((c8 << 3) + j) * 136 + n];
        *reinterpret_cast<us8*>(&outp[(size_t)n * SS + k0 + (c8 << 3)]) = o;
    }
}

// ---------------------------------------------------------------------------
// flashA: LDS-staged (r4 structure), 32 q/wave. grid 512 (B x 16 qblk x 2 kv
// halves, XCD-grouped), 256 thr, 2 blocks/CU. 64-kv tiles, reg prefetch.
// Writes partial unnormalized O (into P region) and partial L.
// ---------------------------------------------------------------------------
__global__ __launch_bounds__(256, 2) void flashA_kernel(
    const unsigned short* __restrict__ Qb, const unsigned short* __restrict__ Kb,
    const unsigned short* __restrict__ VT, const float* __restrict__ maskAdd,
    float* __restrict__ Op0, float* __restrict__ Op1, float* __restrict__ Lp)
{
    __shared__ unsigned short Ks[64 * 128];     // swzA rows (64 kv x 128 d)
    __shared__ unsigned short VTs[128 * 64];    // swzB rows (128 d x 64 kv)
    __shared__ unsigned short Ps[4 * 32 * 64];  // per-wave 32q x 64kv

    const int id = blockIdx.x;
    const int xcd = id & 7, j = id >> 3;
    const int b   = (xcd << 1) | (j >> 5);
    const int rem = j & 31;
    const int half = rem >> 4, qb = rem & 15;
    const int q0 = qb << 7;
    const int kvbase = half << 10;

    const int t = threadIdx.x, lane = t & 63, w = t >> 6;
    const int lr = lane & 15, lg = lane >> 4;

    const unsigned short* Kbb = Kb + (size_t)b * SS * DD;
    const unsigned short* Vbb = VT + (size_t)b * DD * SS;
    const float* Mb = maskAdd + (size_t)b * SS;

    // Q fragments (B-operand): q = q0 + w*32 + m*16 + lr
    const unsigned short* Qp = Qb + ((size_t)b * SS + q0 + w * 32) * DD;
    short8 qf[2][4];
    for (int m = 0; m < 2; ++m)
        for (int kb = 0; kb < 4; ++kb)
            qf[m][kb] = *reinterpret_cast<const short8*>(
                Qp + (size_t)(m * 16 + lr) * DD + kb * 32 + lg * 8);

    f32x4 oacc[2][8] = {};
    float rsum[2] = {0.f, 0.f};
    unsigned short* Pw = &Ps[w * 2048];

    us8 kstg[4], vstg[4];
    {
        for (int i = 0; i < 4; ++i) {
            int f = i * 256 + t;
            kstg[i] = *reinterpret_cast<const us8*>(
                Kbb + (size_t)(kvbase + (f >> 4)) * DD + ((f & 15) << 3));
            vstg[i] = *reinterpret_cast<const us8*>(
                Vbb + (size_t)(f >> 3) * SS + kvbase + ((f & 7) << 3));
        }
    }

    for (int kt = 0; kt < 16; ++kt) {
        const int kv0 = kvbase + (kt << 6);
        __syncthreads();   // all waves done reading previous tile
        for (int i = 0; i < 4; ++i) {
            int f = i * 256 + t;
            *reinterpret_cast<us8*>(&Ks[swzA(f >> 4, (f & 15) << 3)]) = kstg[i];
            *reinterpret_cast<us8*>(&VTs[swzB(f >> 3, (f & 7) << 3)]) = vstg[i];
        }
        __syncthreads();
        if (kt + 1 < 16) {   // T14: issue next-tile loads now, consume next iter
            int nb = kv0 + 64;
            for (int i = 0; i < 4; ++i) {
                int f = i * 256 + t;
                kstg[i] = *reinterpret_cast<const us8*>(
                    Kbb + (size_t)(nb + (f >> 4)) * DD + ((f & 15) << 3));
                vstg[i] = *reinterpret_cast<const us8*>(
                    Vbb + (size_t)(f >> 3) * SS + nb + ((f & 7) << 3));
            }
        }

        // S^T = K . Q^T  (rows = kv, cols = q)
        f32x4 sacc[2][4] = {};
        for (int kb = 0; kb < 4; ++kb) {
            short8 kf[4];
            for (int n = 0; n < 4; ++n)
                kf[n] = *reinterpret_cast<const short8*>(
                    &Ks[swzA(n * 16 + lr, kb * 32 + lg * 8)]);
            for (int n = 0; n < 4; ++n)
                for (int m = 0; m < 2; ++m)
                    sacc[m][n] = __builtin_amdgcn_mfma_f32_16x16x32_bf16(
                        kf[n], qf[m][kb], sacc[m][n], 0, 0, 0);
        }

        // p = 2^(s*CE + maskAdd); rowsum; stash bf16 P (wave-local LDS)
        for (int n = 0; n < 4; ++n) {
            f32x4 ma = *reinterpret_cast<const f32x4*>(Mb + kv0 + n * 16 + lg * 4);
            for (int m = 0; m < 2; ++m) {
                us4 h;
                for (int r = 0; r < 4; ++r) {
                    float p = __builtin_amdgcn_exp2f(fmaf(sacc[m][n][r], CE, ma[r]));
                    rsum[m] += p;
                    h[r] = f2bf(p);
                }
                *reinterpret_cast<us4*>(&Pw[swzB(m * 16 + lr, n * 16 + lg * 4)]) = h;
            }
        }
        asm volatile("s_waitcnt lgkmcnt(0)" ::: "memory");
        __builtin_amdgcn_sched_barrier(0);

        // O += P*V
        for (int k2 = 0; k2 < 2; ++k2) {
            short8 pf[2];
            for (int m = 0; m < 2; ++m)
                pf[m] = *reinterpret_cast<const short8*>(
                    &Pw[swzB(m * 16 + lr, k2 * 32 + lg * 8)]);
            for (int nd = 0; nd < 8; ++nd) {
                short8 vf = *reinterpret_cast<const short8*>(
                    &VTs[swzB(nd * 16 + lr, k2 * 32 + lg * 8)]);
                for (int m = 0; m < 2; ++m)
                    oacc[m][nd] = __builtin_amdgcn_mfma_f32_16x16x32_bf16(
                        pf[m], vf, oacc[m][nd], 0, 0, 0);
            }
        }
    }

    // reduce L across lg groups; write partial L and unnormalized partial O
    for (int m = 0; m < 2; ++m) {
        rsum[m] += __shfl_xor(rsum[m], 16, 64);
        rsum[m] += __shfl_xor(rsum[m], 32, 64);
    }
    if (lane < 16)
        for (int m = 0; m < 2; ++m)
            Lp[(size_t)half * BB * SS + (size_t)b * SS + q0 + w * 32 + m * 16 + lane] = rsum[m];

    float* Op = half ? Op1 : Op0;
    float* Og = Op + ((size_t)b * SS + q0 + w * 32) * DD;
    for (int m = 0; m < 2; ++m)
        for (int nd = 0; nd < 8; ++nd)
            for (int r = 0; r < 4; ++r)
                Og[(size_t)(m * 16 + lg * 4 + r) * DD + nd * 16 + lr] = oacc[m][nd][r];
}

// ---------------------------------------------------------------------------
// combine: O = (O0+O1)*inv(L0+L1); l2il = log2(1/L) (-inf when L==0).
// ---------------------------------------------------------------------------
__global__ __launch_bounds__(256) void combine_kernel(
    const float* __restrict__ Op0, const float* __restrict__ Op1,
    const float* __restrict__ Lp, float* __restrict__ O, float* __restrict__ l2il)
{
    int i = blockIdx.x * 256 + threadIdx.x;   // f32x4 index
    int row = i >> 5;                         // 32 f32x4 per 128-elem row
    float L = Lp[row] + Lp[BB * SS + row];
    float il = L > 0.f ? 1.f / L : 0.f;
    f32x4 a = reinterpret_cast<const f32x4*>(Op0)[i];
    f32x4 c = reinterpret_cast<const f32x4*>(Op1)[i];
    f32x4 o;
    for (int r = 0; r < 4; ++r) o[r] = (a[r] + c[r]) * il;
    reinterpret_cast<f32x4*>(O)[i] = o;
    if ((i & 31) == 0)
        l2il[row] = L > 0.f ? -__builtin_amdgcn_logf(L) : __int_as_float(0xff800000);
}

// ---------------------------------------------------------------------------
// pstore: recompute S^T bit-identically (same tiles/order as flashA), write
// P = 2^(s*CE + maskAdd + log2invL). grid 1024 (kv-split 4), 256 thr,
// 4 blocks/CU (16 waves/CU) to saturate the 268MB store stream.
// ---------------------------------------------------------------------------
__global__ __launch_bounds__(256, 4) void pstore_kernel(
    const unsigned short* __restrict__ Qb, const unsigned short* __restrict__ Kb,
    const float* __restrict__ maskAdd, const float* __restrict__ l2il,
    float* __restrict__ P)
{
    __shared__ unsigned short Ks[64 * 128];

    const int id = blockIdx.x;
    const int xcd = id & 7, j = id >> 3;          // grid 1024
    const int b   = (xcd << 1) | (j >> 6);
    const int rem = j & 63;
    const int kvq = rem >> 4, qb = rem & 15;
    const int q0 = qb << 7, kvbase = kvq << 9;

    const int t = threadIdx.x, lane = t & 63, w = t >> 6;
    const int lr = lane & 15, lg = lane >> 4;

    const unsigned short* Kbb = Kb + (size_t)b * SS * DD;
    const float* Mb = maskAdd + (size_t)b * SS;

    const unsigned short* Qp = Qb + ((size_t)b * SS + q0 + w * 32) * DD;
    short8 qf[2][4];
    for (int m = 0; m < 2; ++m)
        for (int kb = 0; kb < 4; ++kb)
            qf[m][kb] = *reinterpret_cast<const short8*>(
                Qp + (size_t)(m * 16 + lr) * DD + kb * 32 + lg * 8);

    float lil[2];
    for (int m = 0; m < 2; ++m)
        lil[m] = l2il[(size_t)b * SS + q0 + w * 32 + m * 16 + lr];

    us8 kstg[4];
    for (int i = 0; i < 4; ++i) {
        int f = i * 256 + t;
        kstg[i] = *reinterpret_cast<const us8*>(
            Kbb + (size_t)(kvbase + (f >> 4)) * DD + ((f & 15) << 3));
    }

    for (int kt = 0; kt < 8; ++kt) {
        const int kv0 = kvbase + (kt << 6);
        __syncthreads();
        for (int i = 0; i < 4; ++i) {
            int f = i * 256 + t;
            *reinterpret_cast<us8*>(&Ks[swzA(f >> 4, (f & 15) << 3)]) = kstg[i];
        }
        __syncthreads();
        if (kt + 1 < 8) {
            int nb = kv0 + 64;
            for (int i = 0; i < 4; ++i) {
                int f = i * 256 + t;
                kstg[i] = *reinterpret_cast<const us8*>(
                    Kbb + (size_t)(nb + (f >> 4)) * DD + ((f & 15) << 3));
            }
        }

        // identical structure/order to flashA -> bit-identical sacc
        f32x4 sacc[2][4] = {};
        for (int kb = 0; kb < 4; ++kb) {
            short8 kf[4];
            for (int n = 0; n < 4; ++n)
                kf[n] = *reinterpret_cast<const short8*>(
                    &Ks[swzA(n * 16 + lr, kb * 32 + lg * 8)]);
            for (int n = 0; n < 4; ++n)
                for (int m = 0; m < 2; ++m)
                    sacc[m][n] = __builtin_amdgcn_mfma_f32_16x16x32_bf16(
                        kf[n], qf[m][kb], sacc[m][n], 0, 0, 0);
        }

        for (int m = 0; m < 2; ++m) {
            float* Pp = P + ((size_t)b * SS + q0 + w * 32 + m * 16 + lr) * SS + kv0;
            for (int n = 0; n < 4; ++n) {
                f32x4 ma = *reinterpret_cast<const f32x4*>(Mb + kv0 + n * 16 + lg * 4);
                f32x4 out;
                for (int r = 0; r < 4; ++r)
                    out[r] = __builtin_amdgcn_exp2f(
                        fmaf(sacc[m][n][r], CE, ma[r]) + lil[m]);
                *reinterpret_cast<f32x4*>(Pp + n * 16 + lg * 4) = out;
            }
        }
    }
}

// ---------------------------------------------------------------------------
// Fallback pipeline (no workspace requirements)
// ---------------------------------------------------------------------------
__global__ __launch_bounds__(256) void qk_exp_kernel(
    const float* __restrict__ Q, const float* __restrict__ Kin,
    const int* __restrict__ mask, float* __restrict__ P)
{
    __shared__ unsigned short Qs[128 * 128];
    __shared__ unsigned short Ks[128 * 128];
    const int b  = blockIdx.z;
    const int m0 = blockIdx.y << 7;
    const int n0 = blockIdx.x << 7;
    const int t  = threadIdx.x;
    const float* Qp = Q   + ((size_t)b * SS + m0) * DD;
    const float* Kp = Kin + ((size_t)b * SS + n0) * DD;
    for (int i = 0; i < 16; ++i) {
        int f4  = (i << 8) + t;
        int row = f4 >> 5;
        int col = (f4 & 31) << 2;
        f32x4 q = reinterpret_cast<const f32x4*>(Qp)[f4];
        f32x4 k = reinterpret_cast<const f32x4*>(Kp)[f4];
        us4 qh, kh;
        for (int jj = 0; jj < 4; ++jj) { qh[jj] = f2bf(q[jj]); kh[jj] = f2bf(k[jj]); }
        *reinterpret_cast<us4*>(&Qs[swzA(row, col)]) = qh;
        *reinterpret_cast<us4*>(&Ks[swzA(row, col)]) = kh;
    }
    __syncthreads();
    const int lane = t & 63, wid = t >> 6;
    const int wr = wid >> 1, wc = wid & 1;
    const int lr = lane & 15, lg = lane >> 4;
    f32x4 acc[4][4] = {};
    for (int kb = 0; kb < 4; ++kb) {
        short8 a[4], bq[4];
        int kcol = (kb << 5) + (lg << 3);
        for (int m = 0; m < 4; ++m)
            a[m] = *reinterpret_cast<const short8*>(&Qs[swzA((wr << 6) + (m << 4) + lr, kcol)]);
        for (int n = 0; n < 4; ++n)
            bq[n] = *reinterpret_cast<const short8*>(&Ks[swzA((wc << 6) + (n << 4) + lr, kcol)]);
        for (int m = 0; m < 4; ++m)
            for (int n = 0; n < 4; ++n)
                acc[m][n] = __builtin_amdgcn_mfma_f32_16x16x32_bf16(a[m], bq[n], acc[m][n], 0, 0, 0);
    }
    const int* am = mask + (size_t)b * SS;
    for (int n = 0; n < 4; ++n) {
        int col = n0 + (wc << 6) + (n << 4) + lr;
        bool allow = am[col] != 0;
        for (int m = 0; m < 4; ++m) {
            int rowb = m0 + (wr << 6) + (m << 4) + (lg << 2);
            float* Pp = P + ((size_t)b * SS + rowb) * SS + col;
            for (int r = 0; r < 4; ++r) {
                float p = allow ? __expf(acc[m][n][r] * 0.08838834764831845f) : 0.0f;
                Pp[(size_t)r * SS] = p;
            }
        }
    }
}

__global__ __launch_bounds__(256) void norm_kernel(float* __restrict__ P)
{
    int row  = (blockIdx.x << 2) + (threadIdx.x >> 6);
    int lane = threadIdx.x & 63;
    float* Pr = P + (size_t)row * SS;
    f32x4 v[8];
    float sum = 0.f;
    for (int i = 0; i < 8; ++i) {
        v[i] = reinterpret_cast<f32x4*>(Pr)[(i << 6) + lane];
        sum += v[i][0] + v[i][1] + v[i][2] + v[i][3];
    }
    for (int off = 1; off < 64; off <<= 1) sum += __shfl_xor(sum, off, 64);
    float inv = sum > 0.f ? 1.f / sum : 0.f;
    for (int i = 0; i < 8; ++i) {
        f32x4 wv = v[i];
        for (int jj = 0; jj < 4; ++jj) wv[jj] *= inv;
        reinterpret_cast<f32x4*>(Pr)[(i << 6) + lane] = wv;
    }
}

__global__ __launch_bounds__(256) void pv_fallback_kernel(
    const float* __restrict__ P, const float* __restrict__ V, float* __restrict__ O)
{
    __shared__ unsigned short Ws[64 * 64];
    const int b  = blockIdx.y;
    const int m0 = blockIdx.x << 6;
    const int t  = threadIdx.x, lane = t & 63, wid = t >> 6;
    const int wr = wid >> 1, wc = wid & 1;
    const int lr = lane & 15, lg = lane >> 4;
    const float* Pg = P + ((size_t)b * SS + m0) * SS;
    f32x4 acc[2][4] = {};
    for (int k0 = 0; k0 < SS; k0 += 64) {
        __syncthreads();
        for (int i = 0; i < 4; ++i) {
            int f4  = (i << 8) + t;
            int row = f4 >> 4;
            int col = (f4 & 15) << 2;
            f32x4 wv = *reinterpret_cast<const f32x4*>(Pg + (size_t)row * SS + k0 + col);
            us4 h;
            for (int jj = 0; jj < 4; ++jj) h[jj] = f2bf(wv[jj]);
            *reinterpret_cast<us4*>(&Ws[swzB(row, col)]) = h;
        }
        __syncthreads();
        for (int kk = 0; kk < 64; kk += 32) {
            short8 a[2], bv[4];
            int kcol = kk + (lg << 3);
            for (int m = 0; m < 2; ++m)
                a[m] = *reinterpret_cast<const short8*>(&Ws[swzB((wr << 5) + (m << 4) + lr, kcol)]);
            for (int n = 0; n < 4; ++n) {
                int col = (wc << 6) + (n << 4) + lr;
                const float* vp = V + ((size_t)b * SS + k0 + kcol) * DD + col;
                short8 x;
                for (int jj = 0; jj < 8; ++jj) x[jj] = (short)f2bf(vp[(size_t)jj * DD]);
                bv[n] = x;
            }
            for (int m = 0; m < 2; ++m)
                for (int n = 0; n < 4; ++n)
                    acc[m][n] = __builtin_amdgcn_mfma_f32_16x16x32_bf16(a[m], bv[n], acc[m][n], 0, 0, 0);
        }
    }
    float* Og = O + ((size_t)b * SS + m0) * DD;
    for (int m = 0; m < 2; ++m)
        for (int n = 0; n < 4; ++n)
            for (int r = 0; r < 4; ++r)
                Og[(size_t)((wr << 5) + (m << 4) + (lg << 2) + r) * DD
                   + (wc << 6) + (n << 4) + lr] = acc[m][n][r];
}

// ---------------------------------------------------------------------------
extern "C" void kernel_launch(void* const* d_in, const int* in_sizes, int n_in,
                              void* d_out, int out_size, void* d_ws, size_t ws_size,
                              hipStream_t stream)
{
    const float* Q  = (const float*)d_in[0];
    const float* K  = (const float*)d_in[1];
    const float* V  = (const float*)d_in[2];
    const int* mask = (const int*)d_in[3];
    float* O = (float*)d_out;
    float* P = O + (size_t)BB * SS * DD;

    const size_t nE = (size_t)BB * SS * DD;   // 4194304 elements per tensor
    const size_t need = 3 * nE * sizeof(unsigned short)
                      + 4 * (size_t)BB * SS * sizeof(float) + 256;

    if (ws_size >= need) {
        unsigned short* Qb = (unsigned short*)d_ws;
        unsigned short* Kb = Qb + nE;
        unsigned short* VT = Kb + nE;
        float* maskAdd = (float*)(VT + nE);
        float* Lp      = maskAdd + (size_t)BB * SS;   // 2 * BB*SS
        float* l2il    = Lp + 2 * (size_t)BB * SS;
        // partial O buffers live in the P region (overwritten by pstore later)
        float* Op0 = P;
        float* Op1 = P + nE;

        conv_bf16_kernel<<<1024, 256, 0, stream>>>(Q, K, mask, Qb, Kb, maskAdd);
        vt_kernel<<<dim3(SS / 64, BB), 256, 0, stream>>>(V, VT);
        flashA_kernel<<<512, 256, 0, stream>>>(Qb, Kb, VT, maskAdd, Op0, Op1, Lp);
        combine_kernel<<<4096, 256, 0, stream>>>(Op0, Op1, Lp, O, l2il);
        pstore_kernel<<<1024, 256, 0, stream>>>(Qb, Kb, maskAdd, l2il, P);
    } else {
        qk_exp_kernel<<<dim3(SS / 128, SS / 128, BB), 256, 0, stream>>>(Q, K, mask, P);
        norm_kernel<<<(BB * SS) / 4, 256, 0, stream>>>(P);
        pv_fallback_kernel<<<dim3(SS / 64, BB), 256, 0, stream>>>(P, V, O);
    }
}

// Round 7
// 138.756 us; speedup vs baseline: 1.9331x; 1.0371x over previous
//
#include <hip/hip_runtime.h>

#define BB 16
#define SS 2048
#define DD 128
// exp(s/sqrt(128)) = 2^(s * CE),  CE = log2(e)/sqrt(128)
#define CE (0.08838834764831845f * 1.4426950408889634f)

typedef __attribute__((ext_vector_type(4))) float f32x4;
typedef __attribute__((ext_vector_type(8))) short short8;
typedef __attribute__((ext_vector_type(4))) unsigned short us4;
typedef __attribute__((ext_vector_type(8))) unsigned short us8;

__device__ inline unsigned short f2bf(float f) {
    unsigned u = __float_as_uint(f);
    u += 0x7fffu + ((u >> 16) & 1u);   // round-to-nearest-even
    return (unsigned short)(u >> 16);
}

// XOR swizzles (swzA: 256B rows; swzB: 128B rows)
__device__ inline int swzA(int row, int col) {
    int byteoff = (row << 8) + ((col >> 3) << 4);
    byteoff ^= (row & 7) << 4;
    return (byteoff >> 1) + (col & 7);
}
__device__ inline int swzB(int row, int col) {
    int byteoff = (row << 7) + ((col >> 3) << 4);
    byteoff ^= (row & 7) << 4;
    return (byteoff >> 1) + (col & 7);
}

// ---------------------------------------------------------------------------
// prep: Q,K fp32 -> bf16; mask -> additive fp32 (0/-inf); V -> VT bf16.
// grid (S/64, B), 256 thr.
// ---------------------------------------------------------------------------
__global__ __launch_bounds__(256) void prep_kernel(
    const float* __restrict__ Q, const float* __restrict__ K,
    const float* __restrict__ V, const int* __restrict__ mask,
    unsigned short* __restrict__ Qb, unsigned short* __restrict__ Kb,
    unsigned short* __restrict__ VT, float* __restrict__ maskAdd)
{
    __shared__ unsigned short tile[64 * 136];
    int b = blockIdx.y, k0 = blockIdx.x << 6;
    int t = threadIdx.x;
    const size_t base = ((size_t)b * SS + k0) * DD;   // 8192 elements

    // Q/K convert (rows k0..k0+63)
    for (int i = 0; i < 8; ++i) {
        int f4 = (i << 8) + t;
        f32x4 q = reinterpret_cast<const f32x4*>(Q + base)[f4];
        f32x4 k = reinterpret_cast<const f32x4*>(K + base)[f4];
        us4 qh, kh;
        for (int j = 0; j < 4; ++j) { qh[j] = f2bf(q[j]); kh[j] = f2bf(k[j]); }
        reinterpret_cast<us4*>(Qb + base)[f4] = qh;
        reinterpret_cast<us4*>(Kb + base)[f4] = kh;
    }
    if (t < 64)
        maskAdd[(size_t)b * SS + k0 + t] =
            mask[(size_t)b * SS + k0 + t] ? 0.0f : __int_as_float(0xff800000);

    // V transpose
    for (int i = 0; i < 8; ++i) {
        int f4 = (i << 8) + t;
        int k  = f4 >> 5;
        int n  = (f4 & 31) << 2;
        f32x4 v = reinterpret_cast<const f32x4*>(V + base)[f4];
        us4 h;
        for (int j = 0; j < 4; ++j) h[j] = f2bf(v[j]);
        *reinterpret_cast<us4*>(&tile[k * 136 + n]) = h;
    }
    __syncthreads();
    unsigned short* outp = VT + (size_t)b * DD * SS;
    for (int i = 0; i < 4; ++i) {
        int id = (i << 8) + t;
        int n  = id >> 3;
        int c8 = id & 7;
        us8 o;
        for (int j = 0; j < 8; ++j) o[j] = tile[((c8 << 3) + j) * 136 + n];
        *reinterpret_cast<us8*>(&outp[(size_t)n * SS + k0 + (c8 << 3)]) = o;
    }
}

// ---------------------------------------------------------------------------
// flashA: double-buffered, ONE barrier per 64-kv tile. grid 512 (B x 16 qblk
// x 2 kv halves, XCD-grouped), 256 thr, 2 blocks/CU (LDS 72KB). 32 q/wave.
// Writes partial unnormalized O (into P region) and partial L.
// ---------------------------------------------------------------------------
__global__ __launch_bounds__(256, 2) void flashA_kernel(
    const unsigned short* __restrict__ Qb, const unsigned short* __restrict__ Kb,
    const unsigned short* __restrict__ VT, const float* __restrict__ maskAdd,
    float* __restrict__ Op0, float* __restrict__ Op1, float* __restrict__ Lp)
{
    __shared__ unsigned short Ks[2][64 * 128];    // 2 x 16 KB
    __shared__ unsigned short VTs[2][128 * 64];   // 2 x 16 KB
    __shared__ unsigned short Ps[4 * 1024];       // per-wave 16q-row x 64col (2 KB)

    const int id = blockIdx.x;
    const int xcd = id & 7, j = id >> 3;
    const int b   = (xcd << 1) | (j >> 5);
    const int rem = j & 31;
    const int half = rem >> 4, qb = rem & 15;
    const int q0 = qb << 7;
    const int kvbase = half << 10;

    const int t = threadIdx.x, lane = t & 63, w = t >> 6;
    const int lr = lane & 15, lg = lane >> 4;

    const unsigned short* Kbb = Kb + (size_t)b * SS * DD;
    const unsigned short* Vbb = VT + (size_t)b * DD * SS;
    const float* Mb = maskAdd + (size_t)b * SS;

    // Q fragments (B-operand): q = q0 + w*32 + m*16 + lr
    const unsigned short* Qp = Qb + ((size_t)b * SS + q0 + w * 32) * DD;
    short8 qf[2][4];
    for (int m = 0; m < 2; ++m)
        for (int kb = 0; kb < 4; ++kb)
            qf[m][kb] = *reinterpret_cast<const short8*>(
                Qp + (size_t)(m * 16 + lr) * DD + kb * 32 + lg * 8);

    f32x4 oacc[2][8] = {};
    float rsum[2] = {0.f, 0.f};
    unsigned short* Pw = &Ps[w * 1024];

    us8 kstg[4], vstg[4];
#define LOADTILE(kv)                                                             \
    for (int i = 0; i < 4; ++i) {                                                \
        int f = i * 256 + t;                                                     \
        kstg[i] = *reinterpret_cast<const us8*>(                                 \
            Kbb + (size_t)((kv) + (f >> 4)) * DD + ((f & 15) << 3));             \
        vstg[i] = *reinterpret_cast<const us8*>(                                 \
            Vbb + (size_t)(f >> 3) * SS + (kv) + ((f & 7) << 3));                \
    }
#define WRITETILE(bf)                                                            \
    for (int i = 0; i < 4; ++i) {                                                \
        int f = i * 256 + t;                                                     \
        *reinterpret_cast<us8*>(&Ks[bf][swzA(f >> 4, (f & 15) << 3)]) = kstg[i]; \
        *reinterpret_cast<us8*>(&VTs[bf][swzB(f >> 3, (f & 7) << 3)]) = vstg[i]; \
    }

    LOADTILE(kvbase);
    WRITETILE(0);

    for (int kt = 0; kt < 16; ++kt) {
        const int cur = kt & 1;
        const int kv0 = kvbase + (kt << 6);
        if (kt + 1 < 16) { LOADTILE(kv0 + 64); }   // T14: latency hides under compute
        __syncthreads();                           // buf[cur] writes visible

        // S^T = K . Q^T  (rows = kv, cols = q) — order identical to pstore
        f32x4 sacc[2][4] = {};
        __builtin_amdgcn_s_setprio(1);
        for (int kb = 0; kb < 4; ++kb) {
            short8 kf[4];
            for (int n = 0; n < 4; ++n)
                kf[n] = *reinterpret_cast<const short8*>(
                    &Ks[cur][swzA(n * 16 + lr, kb * 32 + lg * 8)]);
            for (int n = 0; n < 4; ++n)
                for (int m = 0; m < 2; ++m)
                    sacc[m][n] = __builtin_amdgcn_mfma_f32_16x16x32_bf16(
                        kf[n], qf[m][kb], sacc[m][n], 0, 0, 0);
        }
        __builtin_amdgcn_s_setprio(0);

        // two 32-kv halves: exp -> wave-local P stash -> PV
        for (int h = 0; h < 2; ++h) {
            for (int nl = 0; nl < 2; ++nl) {
                int n = h * 2 + nl;
                f32x4 ma = *reinterpret_cast<const f32x4*>(Mb + kv0 + n * 16 + lg * 4);
                for (int m = 0; m < 2; ++m) {
                    us4 hh;
                    for (int r = 0; r < 4; ++r) {
                        float p = __builtin_amdgcn_exp2f(fmaf(sacc[m][n][r], CE, ma[r]));
                        rsum[m] += p;
                        hh[r] = f2bf(p);
                    }
                    *reinterpret_cast<us4*>(&Pw[swzB(lr, m * 32 + nl * 16 + lg * 4)]) = hh;
                }
            }
            asm volatile("s_waitcnt lgkmcnt(0)" ::: "memory");
            __builtin_amdgcn_sched_barrier(0);

            short8 pf[2];
            for (int m = 0; m < 2; ++m)
                pf[m] = *reinterpret_cast<const short8*>(&Pw[swzB(lr, m * 32 + lg * 8)]);
            __builtin_amdgcn_s_setprio(1);
            for (int nd = 0; nd < 8; ++nd) {
                short8 vf = *reinterpret_cast<const short8*>(
                    &VTs[cur][swzB(nd * 16 + lr, h * 32 + lg * 8)]);
                for (int m = 0; m < 2; ++m)
                    oacc[m][nd] = __builtin_amdgcn_mfma_f32_16x16x32_bf16(
                        pf[m], vf, oacc[m][nd], 0, 0, 0);
            }
            __builtin_amdgcn_s_setprio(0);
        }

        if (kt + 1 < 16) { WRITETILE(cur ^ 1); }   // safe: readers passed barrier above
    }
#undef LOADTILE
#undef WRITETILE

    // reduce L across lg groups; write partial L and unnormalized partial O
    for (int m = 0; m < 2; ++m) {
        rsum[m] += __shfl_xor(rsum[m], 16, 64);
        rsum[m] += __shfl_xor(rsum[m], 32, 64);
    }
    if (lane < 16)
        for (int m = 0; m < 2; ++m)
            Lp[(size_t)half * BB * SS + (size_t)b * SS + q0 + w * 32 + m * 16 + lane] = rsum[m];

    float* Op = half ? Op1 : Op0;
    float* Og = Op + ((size_t)b * SS + q0 + w * 32) * DD;
    for (int m = 0; m < 2; ++m)
        for (int nd = 0; nd < 8; ++nd)
            for (int r = 0; r < 4; ++r)
                Og[(size_t)(m * 16 + lg * 4 + r) * DD + nd * 16 + lr] = oacc[m][nd][r];
}

// ---------------------------------------------------------------------------
// combine: O = (O0+O1)*inv(L0+L1); l2il = log2(1/L) (-inf when L==0).
// ---------------------------------------------------------------------------
__global__ __launch_bounds__(256) void combine_kernel(
    const float* __restrict__ Op0, const float* __restrict__ Op1,
    const float* __restrict__ Lp, float* __restrict__ O, float* __restrict__ l2il)
{
    int i = blockIdx.x * 256 + threadIdx.x;   // f32x4 index
    int row = i >> 5;                         // 32 f32x4 per 128-elem row
    float L = Lp[row] + Lp[BB * SS + row];
    float il = L > 0.f ? 1.f / L : 0.f;
    f32x4 a = reinterpret_cast<const f32x4*>(Op0)[i];
    f32x4 c = reinterpret_cast<const f32x4*>(Op1)[i];
    f32x4 o;
    for (int r = 0; r < 4; ++r) o[r] = (a[r] + c[r]) * il;
    reinterpret_cast<f32x4*>(O)[i] = o;
    if ((i & 31) == 0)
        l2il[row] = L > 0.f ? -__builtin_amdgcn_logf(L) : __int_as_float(0xff800000);
}

// ---------------------------------------------------------------------------
// pstore: double-buffered K staging, ONE barrier per tile. Recomputes S^T
// bit-identically, writes P = 2^(s*CE + maskAdd + log2invL). grid 1024
// (kv-split 4), 256 thr, 4 blocks/CU (LDS 32KB).
// ---------------------------------------------------------------------------
__global__ __launch_bounds__(256, 4) void pstore_kernel(
    const unsigned short* __restrict__ Qb, const unsigned short* __restrict__ Kb,
    const float* __restrict__ maskAdd, const float* __restrict__ l2il,
    float* __restrict__ P)
{
    __shared__ unsigned short Ks[2][64 * 128];

    const int id = blockIdx.x;
    const int xcd = id & 7, j = id >> 3;          // grid 1024
    const int b   = (xcd << 1) | (j >> 6);
    const int rem = j & 63;
    const int kvq = rem >> 4, qb = rem & 15;
    const int q0 = qb << 7, kvbase = kvq << 9;

    const int t = threadIdx.x, lane = t & 63, w = t >> 6;
    const int lr = lane & 15, lg = lane >> 4;

    const unsigned short* Kbb = Kb + (size_t)b * SS * DD;
    const float* Mb = maskAdd + (size_t)b * SS;

    const unsigned short* Qp = Qb + ((size_t)b * SS + q0 + w * 32) * DD;
    short8 qf[2][4];
    for (int m = 0; m < 2; ++m)
        for (int kb = 0; kb < 4; ++kb)
            qf[m][kb] = *reinterpret_cast<const short8*>(
                Qp + (size_t)(m * 16 + lr) * DD + kb * 32 + lg * 8);

    float lil[2];
    for (int m = 0; m < 2; ++m)
        lil[m] = l2il[(size_t)b * SS + q0 + w * 32 + m * 16 + lr];

    us8 kstg[4];
#define LOADK(kv)                                                                \
    for (int i = 0; i < 4; ++i) {                                                \
        int f = i * 256 + t;                                                     \
        kstg[i] = *reinterpret_cast<const us8*>(                                 \
            Kbb + (size_t)((kv) + (f >> 4)) * DD + ((f & 15) << 3));             \
    }
#define WRITEK(bf)                                                               \
    for (int i = 0; i < 4; ++i) {                                                \
        int f = i * 256 + t;                                                     \
        *reinterpret_cast<us8*>(&Ks[bf][swzA(f >> 4, (f & 15) << 3)]) = kstg[i]; \
    }

    LOADK(kvbase);
    WRITEK(0);

    for (int kt = 0; kt < 8; ++kt) {
        const int cur = kt & 1;
        const int kv0 = kvbase + (kt << 6);
        if (kt + 1 < 8) { LOADK(kv0 + 64); }
        __syncthreads();

        // identical structure/order to flashA -> bit-identical sacc
        f32x4 sacc[2][4] = {};
        for (int kb = 0; kb < 4; ++kb) {
            short8 kf[4];
            for (int n = 0; n < 4; ++n)
                kf[n] = *reinterpret_cast<const short8*>(
                    &Ks[cur][swzA(n * 16 + lr, kb * 32 + lg * 8)]);
            for (int n = 0; n < 4; ++n)
                for (int m = 0; m < 2; ++m)
                    sacc[m][n] = __builtin_amdgcn_mfma_f32_16x16x32_bf16(
                        kf[n], qf[m][kb], sacc[m][n], 0, 0, 0);
        }

        for (int m = 0; m < 2; ++m) {
            float* Pp = P + ((size_t)b * SS + q0 + w * 32 + m * 16 + lr) * SS + kv0;
            for (int n = 0; n < 4; ++n) {
                f32x4 ma = *reinterpret_cast<const f32x4*>(Mb + kv0 + n * 16 + lg * 4);
                f32x4 out;
                for (int r = 0; r < 4; ++r)
                    out[r] = __builtin_amdgcn_exp2f(
                        fmaf(sacc[m][n][r], CE, ma[r]) + lil[m]);
                *reinterpret_cast<f32x4*>(Pp + n * 16 + lg * 4) = out;
            }
        }

        if (kt + 1 < 8) { WRITEK(cur ^ 1); }
    }
#undef LOADK
#undef WRITEK
}

// ---------------------------------------------------------------------------
// Fallback pipeline (no workspace requirements)
// ---------------------------------------------------------------------------
__global__ __launch_bounds__(256) void qk_exp_kernel(
    const float* __restrict__ Q, const float* __restrict__ Kin,
    const int* __restrict__ mask, float* __restrict__ P)
{
    __shared__ unsigned short Qs[128 * 128];
    __shared__ unsigned short Ks[128 * 128];
    const int b  = blockIdx.z;
    const int m0 = blockIdx.y << 7;
    const int n0 = blockIdx.x << 7;
    const int t  = threadIdx.x;
    const float* Qp = Q   + ((size_t)b * SS + m0) * DD;
    const float* Kp = Kin + ((size_t)b * SS + n0) * DD;
    for (int i = 0; i < 16; ++i) {
        int f4  = (i << 8) + t;
        int row = f4 >> 5;
        int col = (f4 & 31) << 2;
        f32x4 q = reinterpret_cast<const f32x4*>(Qp)[f4];
        f32x4 k = reinterpret_cast<const f32x4*>(Kp)[f4];
        us4 qh, kh;
        for (int jj = 0; jj < 4; ++jj) { qh[jj] = f2bf(q[jj]); kh[jj] = f2bf(k[jj]); }
        *reinterpret_cast<us4*>(&Qs[swzA(row, col)]) = qh;
        *reinterpret_cast<us4*>(&Ks[swzA(row, col)]) = kh;
    }
    __syncthreads();
    const int lane = t & 63, wid = t >> 6;
    const int wr = wid >> 1, wc = wid & 1;
    const int lr = lane & 15, lg = lane >> 4;
    f32x4 acc[4][4] = {};
    for (int kb = 0; kb < 4; ++kb) {
        short8 a[4], bq[4];
        int kcol = (kb << 5) + (lg << 3);
        for (int m = 0; m < 4; ++m)
            a[m] = *reinterpret_cast<const short8*>(&Qs[swzA((wr << 6) + (m << 4) + lr, kcol)]);
        for (int n = 0; n < 4; ++n)
            bq[n] = *reinterpret_cast<const short8*>(&Ks[swzA((wc << 6) + (n << 4) + lr, kcol)]);
        for (int m = 0; m < 4; ++m)
            for (int n = 0; n < 4; ++n)
                acc[m][n] = __builtin_amdgcn_mfma_f32_16x16x32_bf16(a[m], bq[n], acc[m][n], 0, 0, 0);
    }
    const int* am = mask + (size_t)b * SS;
    for (int n = 0; n < 4; ++n) {
        int col = n0 + (wc << 6) + (n << 4) + lr;
        bool allow = am[col] != 0;
        for (int m = 0; m < 4; ++m) {
            int rowb = m0 + (wr << 6) + (m << 4) + (lg << 2);
            float* Pp = P + ((size_t)b * SS + rowb) * SS + col;
            for (int r = 0; r < 4; ++r) {
                float p = allow ? __expf(acc[m][n][r] * 0.08838834764831845f) : 0.0f;
                Pp[(size_t)r * SS] = p;
            }
        }
    }
}

__global__ __launch_bounds__(256) void norm_kernel(float* __restrict__ P)
{
    int row  = (blockIdx.x << 2) + (threadIdx.x >> 6);
    int lane = threadIdx.x & 63;
    float* Pr = P + (size_t)row * SS;
    f32x4 v[8];
    float sum = 0.f;
    for (int i = 0; i < 8; ++i) {
        v[i] = reinterpret_cast<f32x4*>(Pr)[(i << 6) + lane];
        sum += v[i][0] + v[i][1] + v[i][2] + v[i][3];
    }
    for (int off = 1; off < 64; off <<= 1) sum += __shfl_xor(sum, off, 64);
    float inv = sum > 0.f ? 1.f / sum : 0.f;
    for (int i = 0; i < 8; ++i) {
        f32x4 wv = v[i];
        for (int jj = 0; jj < 4; ++jj) wv[jj] *= inv;
        reinterpret_cast<f32x4*>(Pr)[(i << 6) + lane] = wv;
    }
}

__global__ __launch_bounds__(256) void pv_fallback_kernel(
    const float* __restrict__ P, const float* __restrict__ V, float* __restrict__ O)
{
    __shared__ unsigned short Ws[64 * 64];
    const int b  = blockIdx.y;
    const int m0 = blockIdx.x << 6;
    const int t  = threadIdx.x, lane = t & 63, wid = t >> 6;
    const int wr = wid >> 1, wc = wid & 1;
    const int lr = lane & 15, lg = lane >> 4;
    const float* Pg = P + ((size_t)b * SS + m0) * SS;
    f32x4 acc[2][4] = {};
    for (int k0 = 0; k0 < SS; k0 += 64) {
        __syncthreads();
        for (int i = 0; i < 4; ++i) {
            int f4  = (i << 8) + t;
            int row = f4 >> 4;
            int col = (f4 & 15) << 2;
            f32x4 wv = *reinterpret_cast<const f32x4*>(Pg + (size_t)row * SS + k0 + col);
            us4 h;
            for (int jj = 0; jj < 4; ++jj) h[jj] = f2bf(wv[jj]);
            *reinterpret_cast<us4*>(&Ws[swzB(row, col)]) = h;
        }
        __syncthreads();
        for (int kk = 0; kk < 64; kk += 32) {
            short8 a[2], bv[4];
            int kcol = kk + (lg << 3);
            for (int m = 0; m < 2; ++m)
                a[m] = *reinterpret_cast<const short8*>(&Ws[swzB((wr << 5) + (m << 4) + lr, kcol)]);
            for (int n = 0; n < 4; ++n) {
                int col = (wc << 6) + (n << 4) + lr;
                const float* vp = V + ((size_t)b * SS + k0 + kcol) * DD + col;
                short8 x;
                for (int jj = 0; jj < 8; ++jj) x[jj] = (short)f2bf(vp[(size_t)jj * DD]);
                bv[n] = x;
            }
            for (int m = 0; m < 2; ++m)
                for (int n = 0; n < 4; ++n)
                    acc[m][n] = __builtin_amdgcn_mfma_f32_16x16x32_bf16(a[m], bv[n], acc[m][n], 0, 0, 0);
        }
    }
    float* Og = O + ((size_t)b * SS + m0) * DD;
    for (int m = 0; m < 2; ++m)
        for (int n = 0; n < 4; ++n)
            for (int r = 0; r < 4; ++r)
                Og[(size_t)((wr << 5) + (m << 4) + (lg << 2) + r) * DD
                   + (wc << 6) + (n << 4) + lr] = acc[m][n][r];
}

// ---------------------------------------------------------------------------
extern "C" void kernel_launch(void* const* d_in, const int* in_sizes, int n_in,
                              void* d_out, int out_size, void* d_ws, size_t ws_size,
                              hipStream_t stream)
{
    const float* Q  = (const float*)d_in[0];
    const float* K  = (const float*)d_in[1];
    const float* V  = (const float*)d_in[2];
    const int* mask = (const int*)d_in[3];
    float* O = (float*)d_out;
    float* P = O + (size_t)BB * SS * DD;

    const size_t nE = (size_t)BB * SS * DD;   // 4194304 elements per tensor
    const size_t need = 3 * nE * sizeof(unsigned short)
                      + 4 * (size_t)BB * SS * sizeof(float) + 256;

    if (ws_size >= need) {
        unsigned short* Qb = (unsigned short*)d_ws;
        unsigned short* Kb = Qb + nE;
        unsigned short* VT = Kb + nE;
        float* maskAdd = (float*)(VT + nE);
        float* Lp      = maskAdd + (size_t)BB * SS;   // 2 * BB*SS
        float* l2il    = Lp + 2 * (size_t)BB * SS;
        // partial O buffers live in the P region (overwritten by pstore later)
        float* Op0 = P;
        float* Op1 = P + nE;

        prep_kernel<<<dim3(SS / 64, BB), 256, 0, stream>>>(Q, K, V, mask, Qb, Kb, VT, maskAdd);
        flashA_kernel<<<512, 256, 0, stream>>>(Qb, Kb, VT, maskAdd, Op0, Op1, Lp);
        combine_kernel<<<4096, 256, 0, stream>>>(Op0, Op1, Lp, O, l2il);
        pstore_kernel<<<1024, 256, 0, stream>>>(Qb, Kb, maskAdd, l2il, P);
    } else {
        qk_exp_kernel<<<dim3(SS / 128, SS / 128, BB), 256, 0, stream>>>(Q, K, mask, P);
        norm_kernel<<<(BB * SS) / 4, 256, 0, stream>>>(P);
        pv_fallback_kernel<<<dim3(SS / 64, BB), 256, 0, stream>>>(P, V, O);
    }
}